// Round 10
// baseline (40.078 us; speedup 1.0000x reference)
//
#include <hip/hip_runtime.h>

#define N_SRC_C   100000
#define N_DST_C   50000
#define N_EDGES_C 800000
#define D_C       64
// h_neigh = (1-ALPHA)*HBar + ALPHA*mean   (stop_gradient identity in fwd)
#define ONE_MINUS_ALPHA 0.9f
#define ALPHA_C        0.1f

#define CONV_ITEMS (N_SRC_C * D_C / 4)          // 1.6M float4 -> 4x fp8
#define PREP_BLOCKS ((CONV_ITEMS + 255) / 256)  // 6250

typedef __attribute__((ext_vector_type(8))) short bf16x8;
typedef __attribute__((ext_vector_type(4))) float f32x4;

__device__ __forceinline__ ushort f32_to_bf16(float f) {
    uint u = __float_as_uint(f);
    return (ushort)((u + 0x7fffu + ((u >> 16) & 1u)) >> 16);
}

// f32 -> OCP e4m3fn, RNE, saturate; exact subnormal handling.
__device__ __forceinline__ uint f32_to_fp8(float x) {
    const uint u = __float_as_uint(x);
    const uint s = (u >> 24) & 0x80u;
    const float af = fabsf(x);
    if (af < 0.015625f) {                       // fp8-subnormal region (< 2^-6)
        const uint m = (uint)(int)rintf(af * 512.0f);   // 0..8 (8 -> 0x08 = 2^-6)
        return s | m;
    }
    if (af >= 448.0f) return s | 0x7Eu;         // clamp to max finite 448
    const uint a = u & 0x7fffffffu;
    const uint r = a + 0x7FFFFu + ((a >> 20) & 1u);     // RNE to 3 mantissa bits
    const uint e8 = (r >> 23) - 120u;
    const uint m8 = (r >> 20) & 7u;
    return s | (e8 << 3) | m8;
}

// accumulate 4 fp8 bytes of v into acc[0..3]:
// f = as_float( sign<<31 | payload<<20 ) * 2^120  (exact, subnormals included)
__device__ __forceinline__ void acc_fp8x4(uint v, float* acc) {
    #pragma unroll
    for (int k = 0; k < 4; ++k) {
        const uint t = v << (24 - 8 * k);       // byte k -> bits[31:24]
        const uint f = (t & 0x80000000u) | ((t >> 4) & 0x07F00000u);
        acc[k] = fmaf(__uint_as_float(f), 0x1p120f, acc[k]);
    }
}

// ---------------------------------------------------------------------------
// Prep: (1) H_src f32->fp8 e4m3 gather table (row = 64B), (2) CSR row_ptr,
// (3) W packed into MFMA B-fragment layout (same as R9, proven).
// ---------------------------------------------------------------------------
__global__ __launch_bounds__(256) void prep_kernel(
    const float* __restrict__ H_src, uint* __restrict__ Hf8,   // packed 4/uint
    const int* __restrict__ dst_idx, int* __restrict__ row_ptr,
    const float* __restrict__ W, ushort* __restrict__ WB)
{
    const int t = blockIdx.x * 256 + threadIdx.x;

    if (t < CONV_ITEMS) {                       // H_src -> fp8
        const float4 v = reinterpret_cast<const float4*>(H_src)[t];
        Hf8[t] = f32_to_fp8(v.x) | (f32_to_fp8(v.y) << 8) |
                 (f32_to_fp8(v.z) << 16) | (f32_to_fp8(v.w) << 24);
    }

    if (t < N_EDGES_C) {                        // CSR row_ptr
        const int d = dst_idx[t];
        const int p = (t == 0) ? -1 : dst_idx[t - 1];
        for (int n = p + 1; n <= d; ++n) row_ptr[n] = t;
        if (t == N_EDGES_C - 1) {
            for (int n = d + 1; n <= N_DST_C; ++n) row_ptr[n] = N_EDGES_C;
        }
    }

    if (t < 4 * 4 * 64 * 8) {                   // W -> B-fragment pack (16KB)
        const int j    = t & 7;
        const int lane = (t >> 3) & 63;
        const int ks   = (t >> 9) & 3;
        const int ob   = t >> 11;
        const int o = ob * 16 + (lane & 15);
        const int k = ks * 32 + ((lane >> 4) << 3) + j;
        WB[t] = f32_to_bf16(W[o * 128 + k]);
    }
}

// ---------------------------------------------------------------------------
// FUSED mean + linear. Block = 256 threads = 4 waves = 64 nodes.
// Gather phase: wave = 16 nodes (group g = 4 lanes owns node base+w*16+g;
//   lane c = lane&3 owns features [16c,16c+16)). One uint4 gather = 16 fp8
//   rows of 64B (2x rows/instr and 1/2 bytes vs R9's bf16). 16-deep batches,
//   indices preloaded one iteration ahead (4 regs/lane, shfl-distributed).
// Epilogue: CV-blend with HBar; write f32 h_neigh; stage bf16 X row
//   [H_dst | h_neigh] into LDS.
// MFMA phase (after barrier): wave w -> 16-node tile w, all 4 output blocks
//   = 16 x mfma_f32_16x16x32_bf16; bias+relu; coalesced-ish stores.
// Tail block: clamp node -> duplicate IDENTICAL writes (deterministic).
// ---------------------------------------------------------------------------
__global__ __launch_bounds__(256) void sage_fused_kernel(
    const uchar*  __restrict__ Hf8,      // fp8 H_src [N_SRC][64]
    const float*  __restrict__ H_dst,
    const float*  __restrict__ HBar,
    const int*    __restrict__ src_idx,
    const int*    __restrict__ row_ptr,
    const ushort* __restrict__ WB,       // packed B-frags [4][4][64][8] bf16
    const float*  __restrict__ b,        // [64]
    float*        __restrict__ h_out,    // [N_DST][64] f32
    float*        __restrict__ hn_out)   // [N_DST][64] f32
{
    __shared__ __align__(16) ushort Xs[64][136];   // 17.4KB, pad 128+8

    const int lane = threadIdx.x & 63;
    const int w    = threadIdx.x >> 6;
    const int g    = lane >> 2;                    // node slot 0..15
    const int c    = lane & 3;                     // feature chunk: [16c,16c+16)
    const int base = blockIdx.x * 64;
    const int r    = w * 16 + g;                   // local X row 0..63
    int node = base + r;
    if (node > N_DST_C - 1) node = N_DST_C - 1;    // tail: duplicate identical work

    const int s0 = row_ptr[node];
    const int s1 = row_ptr[node + 1];

    float acc[16];
    #pragma unroll
    for (int i = 0; i < 16; ++i) acc[i] = 0.f;

    // preload 16 edge indices for this group: lane c holds edges s0+4c+k
    int idxA[4];
    #pragma unroll
    for (int k = 0; k < 4; ++k) idxA[k] = 0;
    if (s0 < s1) {
        #pragma unroll
        for (int k = 0; k < 4; ++k) {
            int p = s0 + 4 * c + k; if (p >= s1) p = s1 - 1;
            idxA[k] = src_idx[p];
        }
    }

    for (int e = s0; e < s1; e += 16) {
        int idxN[4];
        #pragma unroll
        for (int k = 0; k < 4; ++k) idxN[k] = 0;
        if (e + 16 < s1) {
            #pragma unroll
            for (int k = 0; k < 4; ++k) {
                int p = e + 16 + 4 * c + k; if (p >= s1) p = s1 - 1;
                idxN[k] = src_idx[p];
            }
        }
        #pragma unroll
        for (int j = 0; j < 16; ++j) {
            const int ij = __shfl(idxA[j & 3], (lane & 0x3C) | (j >> 2));
            if (e + j < s1) {
                const uint4 p = *reinterpret_cast<const uint4*>(
                    Hf8 + (size_t)ij * 64 + c * 16);
                acc_fp8x4(p.x, acc + 0);
                acc_fp8x4(p.y, acc + 4);
                acc_fp8x4(p.z, acc + 8);
                acc_fp8x4(p.w, acc + 12);
            }
        }
        idxA[0] = idxN[0]; idxA[1] = idxN[1];
        idxA[2] = idxN[2]; idxA[3] = idxN[3];
    }

    const int cnt = s1 - s0;
    const float inv = (cnt > 0) ? (ALPHA_C / (float)cnt) : 0.0f;

    const size_t hbase = (size_t)node * D_C + c * 16;
    float o[16];
    #pragma unroll
    for (int t4 = 0; t4 < 4; ++t4) {
        const float4 hb = *reinterpret_cast<const float4*>(HBar + hbase + t4 * 4);
        o[t4 * 4 + 0] = ONE_MINUS_ALPHA * hb.x + acc[t4 * 4 + 0] * inv;
        o[t4 * 4 + 1] = ONE_MINUS_ALPHA * hb.y + acc[t4 * 4 + 1] * inv;
        o[t4 * 4 + 2] = ONE_MINUS_ALPHA * hb.z + acc[t4 * 4 + 2] * inv;
        o[t4 * 4 + 3] = ONE_MINUS_ALPHA * hb.w + acc[t4 * 4 + 3] * inv;
        *reinterpret_cast<float4*>(hn_out + hbase + t4 * 4) =
            make_float4(o[t4 * 4 + 0], o[t4 * 4 + 1], o[t4 * 4 + 2], o[t4 * 4 + 3]);
    }

    // stage X row r: high half (h_neigh) + low half (H_dst), bf16
    union { ushort u[8]; bf16x8 v; } pk;
    #pragma unroll
    for (int i = 0; i < 8; ++i) pk.u[i] = f32_to_bf16(o[i]);
    *reinterpret_cast<bf16x8*>(&Xs[r][64 + c * 16]) = pk.v;
    #pragma unroll
    for (int i = 0; i < 8; ++i) pk.u[i] = f32_to_bf16(o[8 + i]);
    *reinterpret_cast<bf16x8*>(&Xs[r][64 + c * 16 + 8]) = pk.v;

    #pragma unroll
    for (int half = 0; half < 2; ++half) {
        const float4 d0 = *reinterpret_cast<const float4*>(H_dst + hbase + half * 8);
        const float4 d1 = *reinterpret_cast<const float4*>(H_dst + hbase + half * 8 + 4);
        pk.u[0] = f32_to_bf16(d0.x); pk.u[1] = f32_to_bf16(d0.y);
        pk.u[2] = f32_to_bf16(d0.z); pk.u[3] = f32_to_bf16(d0.w);
        pk.u[4] = f32_to_bf16(d1.x); pk.u[5] = f32_to_bf16(d1.y);
        pk.u[6] = f32_to_bf16(d1.z); pk.u[7] = f32_to_bf16(d1.w);
        *reinterpret_cast<bf16x8*>(&Xs[r][c * 16 + half * 8]) = pk.v;
    }

    __syncthreads();

    // ---- MFMA phase: wave w -> tile w (16 nodes), output blocks 0..3 ----
    const int row16 = lane & 15;
    const int kg    = lane >> 4;

    bf16x8 af[4];
    #pragma unroll
    for (int ks = 0; ks < 4; ++ks)
        af[ks] = *reinterpret_cast<const bf16x8*>(&Xs[w * 16 + row16][kg * 8 + ks * 32]);

    #pragma unroll
    for (int ob = 0; ob < 4; ++ob) {
        f32x4 cacc = {0.f, 0.f, 0.f, 0.f};
        #pragma unroll
        for (int ks = 0; ks < 4; ++ks) {
            const bf16x8 bf = *reinterpret_cast<const bf16x8*>(
                WB + ((size_t)(ob * 4 + ks) * 64 + lane) * 8);
            cacc = __builtin_amdgcn_mfma_f32_16x16x32_bf16(af[ks], bf, cacc, 0, 0, 0);
        }
        const float bias = b[ob * 16 + row16];
        #pragma unroll
        for (int rr = 0; rr < 4; ++rr) {
            int gn = base + w * 16 + kg * 4 + rr;
            if (gn > N_DST_C - 1) gn = N_DST_C - 1;   // duplicate identical value
            h_out[(size_t)gn * D_C + ob * 16 + row16] = fmaxf(cacc[rr] + bias, 0.0f);
        }
    }
}

// ---------------------------------------------------------------------------
extern "C" void kernel_launch(void* const* d_in, const int* in_sizes, int n_in,
                              void* d_out, int out_size, void* d_ws, size_t ws_size,
                              hipStream_t stream) {
    const float* H_src   = (const float*)d_in[0];
    const float* H_dst   = (const float*)d_in[1];
    const float* HBar    = (const float*)d_in[2];
    const int*   src_idx = (const int*)d_in[3];
    const int*   dst_idx = (const int*)d_in[4];
    const float* W       = (const float*)d_in[5];
    const float* b       = (const float*)d_in[6];

    float* out    = (float*)d_out;
    float* h_out  = out;                             // [N_DST][64]
    float* hn_out = out + (size_t)N_DST_C * D_C;     // [N_DST][64]

    // ws: row_ptr @0 (200KB), WB @256KB (16KB), Hf8 @512KB (6.4MB)
    int*    row_ptr = (int*)d_ws;
    ushort* WB      = (ushort*)((char*)d_ws + (256 << 10));
    uint*   Hf8     = (uint*)((char*)d_ws + (512 << 10));

    hipLaunchKernelGGL(prep_kernel, dim3(PREP_BLOCKS), dim3(256), 0, stream,
                       H_src, Hf8, dst_idx, row_ptr, W, WB);

    // 64 nodes/block -> 782 blocks (tail clamped)
    hipLaunchKernelGGL(sage_fused_kernel, dim3((N_DST_C + 63) / 64), dim3(256), 0, stream,
                       (const uchar*)Hf8, H_dst, HBar, src_idx, row_ptr, WB, b,
                       h_out, hn_out);
}

// Round 11
// 37.434 us; speedup vs baseline: 1.0706x; 1.0706x over previous
//
#include <hip/hip_runtime.h>

#define N_SRC_C   100000
#define N_DST_C   50000
#define N_EDGES_C 800000
#define D_C       64
// h_neigh = (1-ALPHA)*HBar + ALPHA*mean   (stop_gradient identity in fwd)
#define ONE_MINUS_ALPHA 0.9f
#define ALPHA_C        0.1f

#define CONV_ITEMS (N_SRC_C * D_C / 4)          // 1,600,000 float4 -> ushort4
#define PREP_BLOCKS ((CONV_ITEMS + 255) / 256)  // 6250

typedef __attribute__((ext_vector_type(8))) short bf16x8;
typedef __attribute__((ext_vector_type(4))) float f32x4;

__device__ __forceinline__ ushort f32_to_bf16(float f) {
    uint u = __float_as_uint(f);
    return (ushort)((u + 0x7fffu + ((u >> 16) & 1u)) >> 16);
}

// ---------------------------------------------------------------------------
// Prep: (1) H_src f32->bf16 gather table (row = 128B = one cache line),
// (2) CSR row_ptr from sorted dst_idx, (3) W packed into MFMA B-frag layout.
// ---------------------------------------------------------------------------
__global__ __launch_bounds__(256) void prep_kernel(
    const float* __restrict__ H_src, ushort* __restrict__ Hb,
    const int* __restrict__ dst_idx, int* __restrict__ row_ptr,
    const float* __restrict__ W, ushort* __restrict__ WB)
{
    const int t = blockIdx.x * 256 + threadIdx.x;

    if (t < CONV_ITEMS) {                       // H_src -> bf16 (RNE)
        const float4 v = reinterpret_cast<const float4*>(H_src)[t];
        ushort4 o;
        o.x = f32_to_bf16(v.x); o.y = f32_to_bf16(v.y);
        o.z = f32_to_bf16(v.z); o.w = f32_to_bf16(v.w);
        reinterpret_cast<ushort4*>(Hb)[t] = o;
    }

    if (t < N_EDGES_C) {                        // CSR row_ptr
        const int d = dst_idx[t];
        const int p = (t == 0) ? -1 : dst_idx[t - 1];
        for (int n = p + 1; n <= d; ++n) row_ptr[n] = t;
        if (t == N_EDGES_C - 1) {
            for (int n = d + 1; n <= N_DST_C; ++n) row_ptr[n] = N_EDGES_C;
        }
    }

    if (t < 4 * 4 * 64 * 8) {                   // W -> B-fragment pack (16KB)
        const int j    = t & 7;
        const int lane = (t >> 3) & 63;
        const int ks   = (t >> 9) & 3;
        const int ob   = t >> 11;
        const int o = ob * 16 + (lane & 15);
        const int k = ks * 32 + ((lane >> 4) << 3) + j;
        WB[t] = f32_to_bf16(W[o * 128 + k]);
    }
}

// ---------------------------------------------------------------------------
// FUSED mean + linear (R9 structure; gather loop de-predicated).
// Block = 256 threads = 4 waves = 32 nodes.
// Gather: 8 nodes/wave (group g = 8 lanes owns node base+w*8+g; lane c owns
//   features [8c,8c+8)). Indices preloaded coalesced one iteration ahead and
//   CLAMPED to s1-1 -> all 16 row-gathers per iteration are UNCONDITIONAL,
//   issued back-to-back into temporaries before any accumulation; validity
//   folds into the accumulate as fmaf(val, w_j, acc), w_j in {0,1}. Zero
//   divergence in front of the loads -> max outstanding requests per wave.
// Epilogue: CV-blend; write f32 h_neigh; stage bf16 X=[H_dst|h_neigh] in LDS.
// MFMA (after barrier): wave w -> tile (w>>1), output blocks {2(w&1),+1};
//   8x mfma_f32_16x16x32_bf16; bias+relu; store.
// ---------------------------------------------------------------------------
__global__ __launch_bounds__(256) void sage_fused_kernel(
    const ushort* __restrict__ Hb,       // bf16 H_src [N_SRC][64]
    const float*  __restrict__ H_dst,
    const float*  __restrict__ HBar,
    const int*    __restrict__ src_idx,
    const int*    __restrict__ row_ptr,
    const ushort* __restrict__ WB,       // packed B-frags [4][4][64][8] bf16
    const float*  __restrict__ b,        // [64]
    float*        __restrict__ h_out,    // [N_DST][64] f32
    float*        __restrict__ hn_out)   // [N_DST][64] f32
{
    __shared__ __align__(16) ushort Xs[32][136];   // 8.7KB, 136 = 128 + 8 pad

    const int lane = threadIdx.x & 63;
    const int w    = threadIdx.x >> 6;
    const int g    = lane >> 3;                    // node slot 0..7
    const int c    = lane & 7;                     // feature chunk
    const int base = blockIdx.x * 32;
    const int r    = w * 8 + g;                    // local X row 0..31
    int node = base + r;
    if (node > N_DST_C - 1) node = N_DST_C - 1;    // tail: duplicate identical work

    const int s0 = row_ptr[node];
    const int s1 = row_ptr[node + 1];

    float acc[8];
    #pragma unroll
    for (int i = 0; i < 8; ++i) acc[i] = 0.f;

    // preload 16 edge indices (lane c holds edges e+c, e+8+c; clamped valid)
    int idxA = 0, idxB = 0;
    if (s0 < s1) {
        int pA = s0 + c;     if (pA >= s1) pA = s1 - 1;
        int pB = s0 + 8 + c; if (pB >= s1) pB = s1 - 1;
        idxA = src_idx[pA];
        idxB = src_idx[pB];
    }

    for (int e = s0; e < s1; e += 16) {
        int nA = idxA, nB = idxB;
        if (e + 16 < s1) {
            int pA = e + 16 + c; if (pA >= s1) pA = s1 - 1;
            int pB = e + 24 + c; if (pB >= s1) pB = s1 - 1;
            nA = src_idx[pA];
            nB = src_idx[pB];
        }

        // issue all 16 gathers unconditionally, back-to-back
        uint4 ld[16];
        #pragma unroll
        for (int j = 0; j < 8; ++j) {
            const int ij = __shfl(idxA, g * 8 + j);
            ld[j] = *reinterpret_cast<const uint4*>(Hb + (size_t)ij * D_C + c * 8);
        }
        #pragma unroll
        for (int j = 0; j < 8; ++j) {
            const int ij = __shfl(idxB, g * 8 + j);
            ld[8 + j] = *reinterpret_cast<const uint4*>(Hb + (size_t)ij * D_C + c * 8);
        }

        // weighted accumulate (w_j in {0,1}): same VALU count as unpack+add
        #pragma unroll
        for (int j = 0; j < 16; ++j) {
            const float wj = (e + j < s1) ? 1.0f : 0.0f;
            const uint4 p = ld[j];
            acc[0] = fmaf(__uint_as_float(p.x << 16),         wj, acc[0]);
            acc[1] = fmaf(__uint_as_float(p.x & 0xffff0000u), wj, acc[1]);
            acc[2] = fmaf(__uint_as_float(p.y << 16),         wj, acc[2]);
            acc[3] = fmaf(__uint_as_float(p.y & 0xffff0000u), wj, acc[3]);
            acc[4] = fmaf(__uint_as_float(p.z << 16),         wj, acc[4]);
            acc[5] = fmaf(__uint_as_float(p.z & 0xffff0000u), wj, acc[5]);
            acc[6] = fmaf(__uint_as_float(p.w << 16),         wj, acc[6]);
            acc[7] = fmaf(__uint_as_float(p.w & 0xffff0000u), wj, acc[7]);
        }
        idxA = nA; idxB = nB;
    }

    const int cnt = s1 - s0;
    const float inv = (cnt > 0) ? (ALPHA_C / (float)cnt) : 0.0f;

    const size_t hbase = (size_t)node * D_C + c * 8;
    const float4 hb0 = *reinterpret_cast<const float4*>(HBar + hbase);
    const float4 hb1 = *reinterpret_cast<const float4*>(HBar + hbase + 4);
    float o[8];
    o[0] = ONE_MINUS_ALPHA * hb0.x + acc[0] * inv;
    o[1] = ONE_MINUS_ALPHA * hb0.y + acc[1] * inv;
    o[2] = ONE_MINUS_ALPHA * hb0.z + acc[2] * inv;
    o[3] = ONE_MINUS_ALPHA * hb0.w + acc[3] * inv;
    o[4] = ONE_MINUS_ALPHA * hb1.x + acc[4] * inv;
    o[5] = ONE_MINUS_ALPHA * hb1.y + acc[5] * inv;
    o[6] = ONE_MINUS_ALPHA * hb1.z + acc[6] * inv;
    o[7] = ONE_MINUS_ALPHA * hb1.w + acc[7] * inv;

    *reinterpret_cast<float4*>(hn_out + hbase)     = make_float4(o[0], o[1], o[2], o[3]);
    *reinterpret_cast<float4*>(hn_out + hbase + 4) = make_float4(o[4], o[5], o[6], o[7]);

    // stage X row r: high half (h_neigh) from registers, low half from H_dst
    union { ushort u[8]; bf16x8 v; } hi, lo;
    #pragma unroll
    for (int i = 0; i < 8; ++i) hi.u[i] = f32_to_bf16(o[i]);
    *reinterpret_cast<bf16x8*>(&Xs[r][64 + c * 8]) = hi.v;

    const float4 d0 = *reinterpret_cast<const float4*>(H_dst + hbase);
    const float4 d1 = *reinterpret_cast<const float4*>(H_dst + hbase + 4);
    lo.u[0] = f32_to_bf16(d0.x); lo.u[1] = f32_to_bf16(d0.y);
    lo.u[2] = f32_to_bf16(d0.z); lo.u[3] = f32_to_bf16(d0.w);
    lo.u[4] = f32_to_bf16(d1.x); lo.u[5] = f32_to_bf16(d1.y);
    lo.u[6] = f32_to_bf16(d1.z); lo.u[7] = f32_to_bf16(d1.w);
    *reinterpret_cast<bf16x8*>(&Xs[r][c * 8]) = lo.v;

    __syncthreads();

    // ---- MFMA phase: wave w -> tile (w>>1), output blocks ob0, ob0+1 ----
    const int tile  = w >> 1;
    const int ob0   = (w & 1) * 2;
    const int row16 = lane & 15;
    const int kg    = lane >> 4;

    bf16x8 af[4];
    #pragma unroll
    for (int ks = 0; ks < 4; ++ks)
        af[ks] = *reinterpret_cast<const bf16x8*>(&Xs[tile * 16 + row16][kg * 8 + ks * 32]);

    #pragma unroll
    for (int oi = 0; oi < 2; ++oi) {
        const int ob = ob0 + oi;
        f32x4 cacc = {0.f, 0.f, 0.f, 0.f};
        #pragma unroll
        for (int ks = 0; ks < 4; ++ks) {
            const bf16x8 bf = *reinterpret_cast<const bf16x8*>(
                WB + ((size_t)(ob * 4 + ks) * 64 + lane) * 8);
            cacc = __builtin_amdgcn_mfma_f32_16x16x32_bf16(af[ks], bf, cacc, 0, 0, 0);
        }
        const float bias = b[ob * 16 + row16];
        #pragma unroll
        for (int rr = 0; rr < 4; ++rr) {
            int gn = base + tile * 16 + kg * 4 + rr;
            if (gn > N_DST_C - 1) gn = N_DST_C - 1;   // duplicate identical value
            h_out[(size_t)gn * D_C + ob * 16 + row16] = fmaxf(cacc[rr] + bias, 0.0f);
        }
    }
}

// ---------------------------------------------------------------------------
extern "C" void kernel_launch(void* const* d_in, const int* in_sizes, int n_in,
                              void* d_out, int out_size, void* d_ws, size_t ws_size,
                              hipStream_t stream) {
    const float* H_src   = (const float*)d_in[0];
    const float* H_dst   = (const float*)d_in[1];
    const float* HBar    = (const float*)d_in[2];
    const int*   src_idx = (const int*)d_in[3];
    const int*   dst_idx = (const int*)d_in[4];
    const float* W       = (const float*)d_in[5];
    const float* b       = (const float*)d_in[6];

    float* out    = (float*)d_out;
    float* h_out  = out;                             // [N_DST][64]
    float* hn_out = out + (size_t)N_DST_C * D_C;     // [N_DST][64]

    // ws: row_ptr @0 (200KB), WB @256KB (16KB), Hb @512KB (12.8MB)
    int*    row_ptr = (int*)d_ws;
    ushort* WB      = (ushort*)((char*)d_ws + (256 << 10));
    ushort* Hb      = (ushort*)((char*)d_ws + (512 << 10));

    hipLaunchKernelGGL(prep_kernel, dim3(PREP_BLOCKS), dim3(256), 0, stream,
                       H_src, Hb, dst_idx, row_ptr, W, WB);

    // 32 nodes/block -> 1563 blocks (tail clamped)
    hipLaunchKernelGGL(sage_fused_kernel, dim3((N_DST_C + 31) / 32), dim3(256), 0, stream,
                       Hb, H_dst, HBar, src_idx, row_ptr, WB, b, h_out, hn_out);
}